// Round 1
// baseline (1142.384 us; speedup 1.0000x reference)
//
#include <hip/hip_runtime.h>
#include <math.h>

// SimpleGSLModel: B=8192, D=768, TOP_K=5
// Pipeline:
//  1. G = X @ W_g                         (fp32 SGEMM, must be f32-exact: feeds selection)
//  2. Xh/Gh = bf16(X/G)
//  3. s_topk: fused S=relu(G@X^T), blend with A_ecfp, per-row approx top-16 candidates (bf16 MFMA)
//  4. merge partials -> global top-16 candidate indices per row
//  5. refine: exact f32 re-evaluation of 16 candidates, exact top-5 (jax tie-break)
//  6. edges: symmetrized sparse A (canonical-pair dedup), CSR build
//  7. gather: M = D^-1 (A @ X)   (sparse, ~10 nnz/row + diag 1)
//  8. H = gelu(M@W_gcn+b), h1 = gelu(H@W1+b1), h2 = gelu(h1@W2+b2)   (fp32 SGEMM)
//  9. out = h2@W3 + b3

typedef __attribute__((ext_vector_type(8))) short short8v;
typedef __attribute__((ext_vector_type(4))) float f32x4;

__device__ __forceinline__ unsigned short f2bf(float f) {
  unsigned u = __float_as_uint(f);
  u += 0x7fffu + ((u >> 16) & 1u);   // round-to-nearest-even
  return (unsigned short)(u >> 16);
}
__device__ __forceinline__ float gelu_f(float x) {
  return 0.5f * x * (1.f + erff(x * 0.7071067811865475f));
}

// sorted-descending insert, all static indexing (no scratch)
__device__ __forceinline__ void ins16(float v, int j, float (&lv)[16], int (&li)[16]) {
#pragma unroll
  for (int p = 15; p >= 1; --p) {
    bool shiftv = v > lv[p - 1];
    bool here = (v > lv[p]) && !shiftv;
    float nv = shiftv ? lv[p - 1] : (here ? v : lv[p]);
    int ni = shiftv ? li[p - 1] : (here ? j : li[p]);
    lv[p] = nv; li[p] = ni;
  }
  if (v > lv[0]) { lv[0] = v; li[0] = j; }
}

__global__ __launch_bounds__(256) void cvt_bf16(const float* __restrict__ in,
                                                unsigned short* __restrict__ out, int n4) {
  int t = blockIdx.x * 256 + threadIdx.x;
  if (t >= n4) return;
  float4 f = ((const float4*)in)[t];
  ushort4 r;
  r.x = f2bf(f.x); r.y = f2bf(f.y); r.z = f2bf(f.z); r.w = f2bf(f.w);
  ((ushort4*)out)[t] = r;
}

// ---------------- fp32 SGEMM, 128x128 tile, 8x8/thread, EPI: 0=none 1=bias+gelu ----------
template <int EPI>
__global__ __launch_bounds__(256) void sgemm_f32(const float* __restrict__ A,
                                                 const float* __restrict__ Bm,
                                                 const float* __restrict__ bias,
                                                 float* __restrict__ C, int N, int K) {
  __shared__ float As[16][132];
  __shared__ float Bs[16][132];
  const int r0 = blockIdx.x * 128, c0 = blockIdx.y * 128;
  const int tid = threadIdx.x;
  const int tr = tid >> 4, tc = tid & 15;
  float acc[8][8];
#pragma unroll
  for (int i = 0; i < 8; ++i)
#pragma unroll
    for (int j = 0; j < 8; ++j) acc[i][j] = 0.f;

  for (int k0 = 0; k0 < K; k0 += 16) {
#pragma unroll
    for (int s = 0; s < 2; ++s) {
      int ch = tid + s * 256;
      int row = ch >> 2, kq = ch & 3;
      float4 a4 = *(const float4*)(A + (size_t)(r0 + row) * K + k0 + kq * 4);
      As[kq * 4 + 0][row] = a4.x; As[kq * 4 + 1][row] = a4.y;
      As[kq * 4 + 2][row] = a4.z; As[kq * 4 + 3][row] = a4.w;
      int kk = ch >> 5, nq = ch & 31;
      *(float4*)&Bs[kk][nq * 4] = *(const float4*)(Bm + (size_t)(k0 + kk) * N + c0 + nq * 4);
    }
    __syncthreads();
#pragma unroll
    for (int k = 0; k < 16; ++k) {
      float a[8], b[8];
      *(float4*)&a[0] = *(const float4*)&As[k][tr * 8];
      *(float4*)&a[4] = *(const float4*)&As[k][tr * 8 + 4];
      *(float4*)&b[0] = *(const float4*)&Bs[k][tc * 8];
      *(float4*)&b[4] = *(const float4*)&Bs[k][tc * 8 + 4];
#pragma unroll
      for (int i = 0; i < 8; ++i)
#pragma unroll
        for (int j = 0; j < 8; ++j) acc[i][j] = fmaf(a[i], b[j], acc[i][j]);
    }
    __syncthreads();
  }
#pragma unroll
  for (int i = 0; i < 8; ++i) {
    int r = r0 + tr * 8 + i;
#pragma unroll
    for (int jq = 0; jq < 2; ++jq) {
      float v[4];
#pragma unroll
      for (int e = 0; e < 4; ++e) {
        int c = c0 + tc * 8 + jq * 4 + e;
        float x = acc[i][jq * 4 + e];
        if (EPI == 1) x = gelu_f(x + bias[c]);
        v[e] = x;
      }
      *(float4*)(C + (size_t)r * N + c0 + tc * 8 + jq * 4) = *(float4*)v;
    }
  }
}

// ---------------- fused S-GEMM + blend + per-row approx top-16 (bf16 MFMA 16x16x32) -------
// grid (64 row-blocks, 8 col-chunks of 1024), 256 thr = 4 waves (2x2), 128x128 j-tiles
__global__ __launch_bounds__(256) void s_topk(const unsigned short* __restrict__ Gh,
                                              const unsigned short* __restrict__ Xh,
                                              const float* __restrict__ Ae,
                                              const float* __restrict__ ralpha,
                                              float* __restrict__ pv, int* __restrict__ pix) {
  __shared__ __align__(16) unsigned short As[128 * 32];
  __shared__ __align__(16) unsigned short Bs[128 * 32];
  __shared__ float Stile[128][65];
  const int r0 = blockIdx.x * 128;
  const int chunk = blockIdx.y;
  const int tid = threadIdx.x;
  const int lane = tid & 63;
  const int w = tid >> 6;
  const int wr = w >> 1, wc = w & 1;
  const float sa = 1.f / (1.f + expf(-ralpha[0]));
  const float sb = 1.f - sa;
  float lv[16]; int li[16];
#pragma unroll
  for (int q = 0; q < 16; ++q) { lv[q] = -1e30f; li[q] = 0; }
  const int srow = tid & 127, sgrp = tid >> 7;

  for (int jt = 0; jt < 8; ++jt) {
    const int j0 = chunk * 1024 + jt * 128;
    f32x4 acc[4][4];
    const f32x4 zero = {0.f, 0.f, 0.f, 0.f};
#pragma unroll
    for (int fi = 0; fi < 4; ++fi)
#pragma unroll
      for (int fj = 0; fj < 4; ++fj) acc[fi][fj] = zero;

    for (int k0 = 0; k0 < 768; k0 += 32) {
#pragma unroll
      for (int s = 0; s < 2; ++s) {
        int ch = tid + s * 256;
        int row = ch >> 2, kq = ch & 3;
        uint4 av = *(const uint4*)(Gh + (size_t)(r0 + row) * 768 + k0 + kq * 8);
        uint4 bv = *(const uint4*)(Xh + (size_t)(j0 + row) * 768 + k0 + kq * 8);
        int byo = row * 64 + kq * 16;
        byo ^= ((row >> 1) & 3) << 4;   // bank swizzle: row bits 1-2 -> byte bits 4-5
        *(uint4*)((char*)As + byo) = av;
        *(uint4*)((char*)Bs + byo) = bv;
      }
      __syncthreads();
      short8v af[4], bf[4];
#pragma unroll
      for (int f = 0; f < 4; ++f) {
        int rowa = wr * 64 + f * 16 + (lane & 15);
        int ba = rowa * 64 + (lane >> 4) * 16;
        ba ^= ((rowa >> 1) & 3) << 4;
        af[f] = *(const short8v*)((const char*)As + ba);
        int rowb = wc * 64 + f * 16 + (lane & 15);
        int bb = rowb * 64 + (lane >> 4) * 16;
        bb ^= ((rowb >> 1) & 3) << 4;
        bf[f] = *(const short8v*)((const char*)Bs + bb);
      }
#pragma unroll
      for (int fi = 0; fi < 4; ++fi)
#pragma unroll
        for (int fj = 0; fj < 4; ++fj)
          acc[fi][fj] = __builtin_amdgcn_mfma_f32_16x16x32_bf16(af[fi], bf[fj], acc[fi][fj], 0, 0, 0);
      __syncthreads();
    }
    // epilogue: blend with A_ecfp, stage to LDS in two 64-col halves, scan for top-16
#pragma unroll
    for (int h = 0; h < 2; ++h) {
      if (wc == h) {
#pragma unroll
        for (int fi = 0; fi < 4; ++fi)
#pragma unroll
          for (int fj = 0; fj < 4; ++fj)
#pragma unroll
            for (int r = 0; r < 4; ++r) {
              int row = wr * 64 + fi * 16 + (lane >> 4) * 4 + r;
              int col = fj * 16 + (lane & 15);
              float ec = Ae[(size_t)(r0 + row) * 8192 + j0 + h * 64 + col];
              Stile[row][col] = sa * ec + sb * fmaxf(acc[fi][fj][r], 0.f);
            }
      }
      __syncthreads();
      unsigned m = 0;
#pragma unroll
      for (int c = 0; c < 32; ++c) {
        float v = Stile[srow][sgrp * 32 + c];
        if (v > lv[15]) m |= (1u << c);
      }
      while (m) {
        int c = __ffs(m) - 1; m &= m - 1;
        float v = Stile[srow][sgrp * 32 + c];
        if (v > lv[15]) ins16(v, j0 + h * 64 + sgrp * 32 + c, lv, li);
      }
      __syncthreads();
    }
  }
  // merge grp1 list into grp0, write per-(row,chunk) partial top-16
  if (sgrp == 1) {
#pragma unroll
    for (int q = 0; q < 16; ++q) {
      Stile[srow][q] = lv[q];
      Stile[srow][16 + q] = __int_as_float(li[q]);
    }
  }
  __syncthreads();
  if (sgrp == 0) {
#pragma unroll
    for (int q = 0; q < 16; ++q) {
      float v = Stile[srow][q];
      int j = __float_as_int(Stile[srow][16 + q]);
      if (v > lv[15]) ins16(v, j, lv, li);
    }
    size_t base = ((size_t)(r0 + srow) * 8 + chunk) * 16;
#pragma unroll
    for (int q = 0; q < 16; ++q) { pv[base + q] = lv[q]; pix[base + q] = li[q]; }
  }
}

__global__ __launch_bounds__(256) void merge16(const float* __restrict__ pv,
                                               const int* __restrict__ pix,
                                               int* __restrict__ gidx) {
  int row = blockIdx.x * 256 + threadIdx.x;
  float lv[16]; int li[16];
#pragma unroll
  for (int q = 0; q < 16; ++q) { lv[q] = -1e30f; li[q] = 0; }
  for (int ch = 0; ch < 8; ++ch) {
    size_t base = ((size_t)row * 8 + ch) * 16;
#pragma unroll
    for (int q = 0; q < 16; ++q) {
      float v = pv[base + q];
      if (v > lv[15]) ins16(v, pix[base + q], lv, li);
    }
  }
#pragma unroll
  for (int q = 0; q < 16; ++q) gidx[row * 16 + q] = li[q];
}

// exact f32 re-evaluation of 16 candidates, exact top-5 (ties -> lower index). 1 wave/row.
__global__ __launch_bounds__(256) void refine5(const float* __restrict__ G,
                                               const float* __restrict__ X,
                                               const float* __restrict__ Ae,
                                               const int* __restrict__ gidx,
                                               const float* __restrict__ ralpha,
                                               int* __restrict__ t5i, float* __restrict__ t5v) {
  int i = blockIdx.x * 4 + (threadIdx.x >> 6);
  int lane = threadIdx.x & 63;
  int c = lane >> 2, s = lane & 3;
  float sa = 1.f / (1.f + expf(-ralpha[0]));
  int j = gidx[i * 16 + c];
  const float* g = G + (size_t)i * 768;
  const float* x = X + (size_t)j * 768;
  float a = 0.f;
#pragma unroll 8
  for (int t = 0; t < 192; ++t) a = fmaf(g[s + 4 * t], x[s + 4 * t], a);
  a += __shfl_xor(a, 1);
  a += __shfl_xor(a, 2);
  float v = sa * Ae[(size_t)i * 8192 + j] + (1.f - sa) * fmaxf(a, 0.f);
  float vs[16]; int js[16];
#pragma unroll
  for (int q = 0; q < 16; ++q) { vs[q] = __shfl(v, q * 4); js[q] = __shfl(j, q * 4); }
  if (lane == 0) {
    unsigned used = 0;
#pragma unroll
    for (int t = 0; t < 5; ++t) {
      float bv = -1e30f; int bj = 0; int bq = 0; bool any = false;
#pragma unroll
      for (int q = 0; q < 16; ++q) {
        bool ok = ((used >> q) & 1u) == 0u;
        bool better = ok && (!any || vs[q] > bv || (vs[q] == bv && js[q] < bj));
        bv = better ? vs[q] : bv; bj = better ? js[q] : bj; bq = better ? q : bq;
        any = any || better;
      }
      used |= (1u << bq);
      t5v[(size_t)i * 5 + t] = bv;
      t5i[(size_t)i * 5 + t] = bj;
    }
  }
}

// -------- symmetrized sparse-A construction (canonical-pair dedup) --------
__global__ void edge_deg(const int* __restrict__ t5i, int* __restrict__ deg) {
  int e = blockIdx.x * 256 + threadIdx.x;
  if (e >= 40960) return;
  int i = e / 5, t = e - i * 5;
  int j = t5i[i * 5 + t];
  if (j == i) return;
  bool rev = false;
#pragma unroll
  for (int u = 0; u < 5; ++u) rev = rev || (t5i[j * 5 + u] == i);
  if (!rev || i < j) { atomicAdd(&deg[i], 1); atomicAdd(&deg[j], 1); }
}

__global__ void scan8k(const int* __restrict__ deg, int* __restrict__ off) {
  __shared__ int sums[256];
  int tid = threadIdx.x;
  int base = tid * 32;
  int s = 0;
  for (int u = 0; u < 32; ++u) s += deg[base + u];
  sums[tid] = s;
  __syncthreads();
  for (int d = 1; d < 256; d <<= 1) {
    int v = (tid >= d) ? sums[tid - d] : 0;
    __syncthreads();
    sums[tid] += v;
    __syncthreads();
  }
  int run = tid ? sums[tid - 1] : 0;
  for (int u = 0; u < 32; ++u) { off[base + u] = run; run += deg[base + u]; }
  if (tid == 255) off[8192] = run;
}

// one wave per directed edge; recompute reverse value exactly when not reciprocated
__global__ __launch_bounds__(256) void edge_fill(const int* __restrict__ t5i,
                                                 const float* __restrict__ t5v,
                                                 const float* __restrict__ G,
                                                 const float* __restrict__ X,
                                                 const float* __restrict__ Ae,
                                                 const float* __restrict__ ralpha,
                                                 const int* __restrict__ off,
                                                 int* __restrict__ cursor,
                                                 int* __restrict__ ccol, float* __restrict__ cval) {
  int e = blockIdx.x * 4 + (threadIdx.x >> 6);
  if (e >= 40960) return;
  int lane = threadIdx.x & 63;
  int i = e / 5, t = e - i * 5;
  int j = t5i[i * 5 + t];
  if (j == i) return;
  int rev = -1;
#pragma unroll
  for (int u = 0; u < 5; ++u)
    if (t5i[j * 5 + u] == i) rev = u;
  if (!(rev < 0 || i < j)) return;
  float vji;
  if (rev >= 0) {
    vji = t5v[j * 5 + rev];
  } else {
    const float* g = G + (size_t)j * 768;
    const float* x = X + (size_t)i * 768;
    float a = 0.f;
#pragma unroll
    for (int u = 0; u < 12; ++u) a = fmaf(g[lane + 64 * u], x[lane + 64 * u], a);
#pragma unroll
    for (int d = 32; d; d >>= 1) a += __shfl_xor(a, d);
    float sa = 1.f / (1.f + expf(-ralpha[0]));
    vji = sa * Ae[(size_t)j * 8192 + i] + (1.f - sa) * fmaxf(a, 0.f);
  }
  if (lane == 0) {
    float vij = t5v[i * 5 + t];
    int p0 = off[i] + atomicAdd(&cursor[i], 1);
    ccol[p0] = j; cval[p0] = vij;
    int p1 = off[j] + atomicAdd(&cursor[j], 1);
    ccol[p1] = i; cval[p1] = vji;
  }
}

// M = D^-1 * (X[i] + sum val * X[j]) ; one block per row
__global__ __launch_bounds__(256) void gather_gcn(const float* __restrict__ X,
                                                  const int* __restrict__ off,
                                                  const int* __restrict__ ccol,
                                                  const float* __restrict__ cval,
                                                  float* __restrict__ M) {
  __shared__ float red[256];
  __shared__ float sdinv;
  int i = blockIdx.x, tid = threadIdx.x;
  int s0 = off[i], cnt = off[i + 1] - s0;
  float s = 0.f;
  for (int e = tid; e < cnt; e += 256) s += cval[s0 + e];
  red[tid] = s;
  __syncthreads();
  for (int d = 128; d; d >>= 1) {
    if (tid < d) red[tid] += red[tid + d];
    __syncthreads();
  }
  if (tid == 0) sdinv = 1.f / fmaxf(1.f + red[0], 1e-8f);
  __syncthreads();
  float dinv = sdinv;
  const float* xi = X + (size_t)i * 768;
  float a0 = xi[tid], a1 = xi[tid + 256], a2 = xi[tid + 512];
  for (int e = 0; e < cnt; ++e) {
    float v = cval[s0 + e];
    const float* xr = X + (size_t)ccol[s0 + e] * 768;
    a0 = fmaf(v, xr[tid], a0);
    a1 = fmaf(v, xr[tid + 256], a1);
    a2 = fmaf(v, xr[tid + 512], a2);
  }
  float* mi = M + (size_t)i * 768;
  mi[tid] = a0 * dinv; mi[tid + 256] = a1 * dinv; mi[tid + 512] = a2 * dinv;
}

__global__ __launch_bounds__(256) void final_head(const float* __restrict__ h2,
                                                  const float* __restrict__ W3,
                                                  const float* __restrict__ b3,
                                                  float* __restrict__ out) {
  int i = blockIdx.x * 4 + (threadIdx.x >> 6);
  int lane = threadIdx.x & 63;
  const float* r = h2 + (size_t)i * 256;
  float s = r[lane] * W3[lane] + r[lane + 64] * W3[lane + 64] +
            r[lane + 128] * W3[lane + 128] + r[lane + 192] * W3[lane + 192];
#pragma unroll
  for (int d = 32; d; d >>= 1) s += __shfl_xor(s, d);
  if (lane == 0) out[i] = s + b3[0];
}

extern "C" void kernel_launch(void* const* d_in, const int* in_sizes, int n_in,
                              void* d_out, int out_size, void* d_ws, size_t ws_size,
                              hipStream_t stream) {
  const float* X   = (const float*)d_in[0];
  const float* Ae  = (const float*)d_in[1];
  const float* Wg  = (const float*)d_in[2];
  const float* ra  = (const float*)d_in[3];
  const float* Wgc = (const float*)d_in[4];
  const float* bgc = (const float*)d_in[5];
  const float* W1  = (const float*)d_in[6];
  const float* b1  = (const float*)d_in[7];
  const float* W2  = (const float*)d_in[8];
  const float* b2  = (const float*)d_in[9];
  const float* W3  = (const float*)d_in[10];
  const float* b3  = (const float*)d_in[11];
  float* out = (float*)d_out;

  char* w = (char*)d_ws;
  size_t off_ = 0;
  auto take = [&](size_t n) -> void* {
    void* p = w + off_;
    off_ += (n + 255) & ~(size_t)255;
    return p;
  };
  float* G           = (float*)take((size_t)8192 * 768 * 4);
  unsigned short* Xh = (unsigned short*)take((size_t)8192 * 768 * 2);
  unsigned short* Gh = (unsigned short*)take((size_t)8192 * 768 * 2);
  float* pv          = (float*)take((size_t)8192 * 128 * 4);
  int* pix           = (int*)take((size_t)8192 * 128 * 4);
  int* gidx          = (int*)take((size_t)8192 * 16 * 4);
  int* t5i           = (int*)take((size_t)8192 * 5 * 4);
  float* t5v         = (float*)take((size_t)8192 * 5 * 4);
  int* deg           = (int*)take((size_t)8192 * 4);
  int* offr          = (int*)take((size_t)8193 * 4);
  int* cur           = (int*)take((size_t)8192 * 4);
  int* ccol          = (int*)take((size_t)81920 * 4);
  float* cval        = (float*)take((size_t)81920 * 4);
  float* h1          = (float*)take((size_t)8192 * 512 * 4);
  float* h2          = (float*)take((size_t)8192 * 256 * 4);
  float* Mm = (float*)Xh;  // reuse: Xh+Gh (25.2MB contiguous) dead after s_topk
  float* H  = G;           // reuse: G dead after edge_fill

  // 1. G = X @ W_g (f32-exact)
  sgemm_f32<0><<<dim3(64, 6), 256, 0, stream>>>(X, Wg, nullptr, G, 768, 768);
  // 2/3. bf16 copies for candidate pass
  cvt_bf16<<<6144, 256, 0, stream>>>(X, Xh, 8192 * 768 / 4);
  cvt_bf16<<<6144, 256, 0, stream>>>(G, Gh, 8192 * 768 / 4);
  // 4. fused S + blend + approx top-16
  s_topk<<<dim3(64, 8), 256, 0, stream>>>(Gh, Xh, Ae, ra, pv, pix);
  // 5. global candidate merge
  merge16<<<32, 256, 0, stream>>>(pv, pix, gidx);
  // 6. exact refine -> top-5
  refine5<<<2048, 256, 0, stream>>>(G, X, Ae, gidx, ra, t5i, t5v);
  // 7-10. sparse symmetric A as CSR
  hipMemsetAsync(deg, 0, 8192 * 4, stream);
  hipMemsetAsync(cur, 0, 8192 * 4, stream);
  edge_deg<<<160, 256, 0, stream>>>(t5i, deg);
  scan8k<<<1, 256, 0, stream>>>(deg, offr);
  edge_fill<<<10240, 256, 0, stream>>>(t5i, t5v, G, X, Ae, ra, offr, cur, ccol, cval);
  // 11. M = A_norm @ X
  gather_gcn<<<8192, 256, 0, stream>>>(X, offr, ccol, cval, Mm);
  // 12-14. GCN + MLP
  sgemm_f32<1><<<dim3(64, 6), 256, 0, stream>>>(Mm, Wgc, bgc, H, 768, 768);
  sgemm_f32<1><<<dim3(64, 4), 256, 0, stream>>>(H, W1, b1, h1, 512, 768);
  sgemm_f32<1><<<dim3(64, 2), 256, 0, stream>>>(h1, W2, b2, h2, 256, 512);
  // 15. head
  final_head<<<2048, 256, 0, stream>>>(h2, W3, b3, out);

  (void)in_sizes; (void)n_in; (void)out_size; (void)ws_size;
}

// Round 3
// 1030.301 us; speedup vs baseline: 1.1088x; 1.1088x over previous
//
#include <hip/hip_runtime.h>
#include <math.h>

// SimpleGSLModel: B=8192, D=768, TOP_K=5
// R3: selection pipeline restored to R1-proven semantics:
//     - G = X@Wg via R1's verbatim fp32 sgemm (bitwise-identical G -> identical selection)
//     - candidate ranking blends Ae back in (f32, at scan time)
//     Fast machinery kept where selection doesn't care:
//     - s_topk MFMA core (m97-style global_load_lds staging)
//     - H/h1/h2 GEMMs via split-bf16 MFMA (hi/lo planes, 3 passes; value-only ~1e-5 impact)

typedef __attribute__((ext_vector_type(8))) short short8v;
typedef __attribute__((ext_vector_type(4))) float f32x4;

__device__ __forceinline__ unsigned short f2bf(float f) {
  unsigned u = __float_as_uint(f);
  u += 0x7fffu + ((u >> 16) & 1u);   // RNE
  return (unsigned short)(u >> 16);
}
__device__ __forceinline__ float bf2f(unsigned short h) {
  return __uint_as_float(((unsigned)h) << 16);
}
__device__ __forceinline__ float gelu_f(float x) {
  return 0.5f * x * (1.f + erff(x * 0.7071067811865475f));
}
__device__ __forceinline__ void gload16(const void* g, void* l) {
  __builtin_amdgcn_global_load_lds(
      (const __attribute__((address_space(1))) unsigned int*)g,
      (__attribute__((address_space(3))) unsigned int*)l, 16, 0, 0);
}

// sorted-descending insert, static indexing
__device__ __forceinline__ void ins16(float v, int j, float (&lv)[16], int (&li)[16]) {
#pragma unroll
  for (int p = 15; p >= 1; --p) {
    bool shiftv = v > lv[p - 1];
    bool here = (v > lv[p]) && !shiftv;
    float nv = shiftv ? lv[p - 1] : (here ? v : lv[p]);
    int ni = shiftv ? li[p - 1] : (here ? j : li[p]);
    lv[p] = nv; li[p] = ni;
  }
  if (v > lv[0]) { lv[0] = v; li[0] = j; }
}

__global__ __launch_bounds__(256) void cvt_bf16(const float* __restrict__ in,
                                                unsigned short* __restrict__ out, int n4) {
  int t = blockIdx.x * 256 + threadIdx.x;
  if (t >= n4) return;
  float4 f = ((const float4*)in)[t];
  ushort4 r;
  r.x = f2bf(f.x); r.y = f2bf(f.y); r.z = f2bf(f.z); r.w = f2bf(f.w);
  ((ushort4*)out)[t] = r;
}

// f32 -> (hi, lo) bf16 planes
__global__ __launch_bounds__(256) void split_act(const float* __restrict__ in,
                                                 unsigned short* __restrict__ hi,
                                                 unsigned short* __restrict__ lo, int n4) {
  int t = blockIdx.x * 256 + threadIdx.x;
  if (t >= n4) return;
  float4 f = ((const float4*)in)[t];
  ushort4 h, l;
  float x;
  x = f.x; h.x = f2bf(x); l.x = f2bf(x - bf2f(h.x));
  x = f.y; h.y = f2bf(x); l.y = f2bf(x - bf2f(h.y));
  x = f.z; h.z = f2bf(x); l.z = f2bf(x - bf2f(h.z));
  x = f.w; h.w = f2bf(x); l.w = f2bf(x - bf2f(h.w));
  ((ushort4*)hi)[t] = h;
  ((ushort4*)lo)[t] = l;
}

// W [K x N] f32 -> transposed bf16 planes thi/tlo [N x K]
__global__ __launch_bounds__(256) void split_wt(const float* __restrict__ W,
                                                unsigned short* __restrict__ thi,
                                                unsigned short* __restrict__ tlo,
                                                int K, int N) {
  __shared__ float tile[32][33];
  int kb = blockIdx.x * 32, nb = blockIdx.y * 32;
  int tx = threadIdx.x & 31, ty = threadIdx.x >> 5;
#pragma unroll
  for (int p = 0; p < 4; ++p)
    tile[ty + p * 8][tx] = W[(size_t)(kb + ty + p * 8) * N + nb + tx];
  __syncthreads();
#pragma unroll
  for (int p = 0; p < 4; ++p) {
    int n = ty + p * 8;
    float x = tile[tx][n];
    unsigned short h = f2bf(x);
    unsigned short l = f2bf(x - bf2f(h));
    thi[(size_t)(nb + n) * K + kb + tx] = h;
    tlo[(size_t)(nb + n) * K + kb + tx] = l;
  }
}

// ---------------- R1-verbatim fp32 SGEMM (used for G only; rounding must stay identical) ----
template <int EPI>
__global__ __launch_bounds__(256) void sgemm_f32(const float* __restrict__ A,
                                                 const float* __restrict__ Bm,
                                                 const float* __restrict__ bias,
                                                 float* __restrict__ C, int N, int K) {
  __shared__ float As[16][132];
  __shared__ float Bs[16][132];
  const int r0 = blockIdx.x * 128, c0 = blockIdx.y * 128;
  const int tid = threadIdx.x;
  const int tr = tid >> 4, tc = tid & 15;
  float acc[8][8];
#pragma unroll
  for (int i = 0; i < 8; ++i)
#pragma unroll
    for (int j = 0; j < 8; ++j) acc[i][j] = 0.f;

  for (int k0 = 0; k0 < K; k0 += 16) {
#pragma unroll
    for (int s = 0; s < 2; ++s) {
      int ch = tid + s * 256;
      int row = ch >> 2, kq = ch & 3;
      float4 a4 = *(const float4*)(A + (size_t)(r0 + row) * K + k0 + kq * 4);
      As[kq * 4 + 0][row] = a4.x; As[kq * 4 + 1][row] = a4.y;
      As[kq * 4 + 2][row] = a4.z; As[kq * 4 + 3][row] = a4.w;
      int kk = ch >> 5, nq = ch & 31;
      *(float4*)&Bs[kk][nq * 4] = *(const float4*)(Bm + (size_t)(k0 + kk) * N + c0 + nq * 4);
    }
    __syncthreads();
#pragma unroll
    for (int k = 0; k < 16; ++k) {
      float a[8], b[8];
      *(float4*)&a[0] = *(const float4*)&As[k][tr * 8];
      *(float4*)&a[4] = *(const float4*)&As[k][tr * 8 + 4];
      *(float4*)&b[0] = *(const float4*)&Bs[k][tc * 8];
      *(float4*)&b[4] = *(const float4*)&Bs[k][tc * 8 + 4];
#pragma unroll
      for (int i = 0; i < 8; ++i)
#pragma unroll
        for (int j = 0; j < 8; ++j) acc[i][j] = fmaf(a[i], b[j], acc[i][j]);
    }
    __syncthreads();
  }
#pragma unroll
  for (int i = 0; i < 8; ++i) {
    int r = r0 + tr * 8 + i;
#pragma unroll
    for (int jq = 0; jq < 2; ++jq) {
      float v[4];
#pragma unroll
      for (int e = 0; e < 4; ++e) {
        int c = c0 + tc * 8 + jq * 4 + e;
        float x = acc[i][jq * 4 + e];
        if (EPI == 1) x = gelu_f(x + bias[c]);
        v[e] = x;
      }
      *(float4*)(C + (size_t)r * N + c0 + tc * 8 + jq * 4) = *(float4*)v;
    }
  }
}

// ---------- bf16 MFMA GEMM, m97 structure: 128x128 tile, 4 waves, BK=64, gload_lds ----------
// A: M x K bf16 row-major; Bt: N x K bf16 row-major (B transposed); C: M x N f32
template <int ACC, int EPI>
__global__ __launch_bounds__(256) void gemm_bt(const unsigned short* __restrict__ A,
                                               const unsigned short* __restrict__ Bt,
                                               const float* __restrict__ bias,
                                               float* __restrict__ C, int N, int K) {
  __shared__ __align__(16) unsigned short As[128 * 64];
  __shared__ __align__(16) unsigned short Bs[128 * 64];
  const int r0 = blockIdx.x * 128, c0 = blockIdx.y * 128;
  const int tid = threadIdx.x, lane = tid & 63, w = tid >> 6;
  const int wr = w >> 1, wc = w & 1;
  f32x4 acc[4][4];
  const f32x4 z4 = {0.f, 0.f, 0.f, 0.f};
#pragma unroll
  for (int i = 0; i < 4; ++i)
#pragma unroll
    for (int j = 0; j < 4; ++j) acc[i][j] = z4;

  const int srow = w * 32 + (lane >> 3);
  const unsigned short* aSrc = A + (size_t)(r0 + srow) * K + (lane & 7) * 8;
  const unsigned short* bSrc = Bt + (size_t)(c0 + srow) * K + (lane & 7) * 8;

  for (int k0 = 0; k0 < K; k0 += 64) {
#pragma unroll
    for (int t = 0; t < 4; ++t) {
      gload16(aSrc + k0 + (size_t)t * 8 * K, (char*)As + (w * 32 + t * 8) * 128);
      gload16(bSrc + k0 + (size_t)t * 8 * K, (char*)Bs + (w * 32 + t * 8) * 128);
    }
    __syncthreads();
#pragma unroll
    for (int ks = 0; ks < 2; ++ks) {
      short8v af[4], bf[4];
#pragma unroll
      for (int f = 0; f < 4; ++f) {
        af[f] = *(const short8v*)((const char*)As +
                 (wr * 64 + f * 16 + (lane & 15)) * 128 + ks * 64 + (lane >> 4) * 16);
        bf[f] = *(const short8v*)((const char*)Bs +
                 (wc * 64 + f * 16 + (lane & 15)) * 128 + ks * 64 + (lane >> 4) * 16);
      }
#pragma unroll
      for (int fi = 0; fi < 4; ++fi)
#pragma unroll
        for (int fj = 0; fj < 4; ++fj)
          acc[fi][fj] = __builtin_amdgcn_mfma_f32_16x16x32_bf16(af[fi], bf[fj], acc[fi][fj], 0, 0, 0);
    }
    __syncthreads();
  }
#pragma unroll
  for (int fi = 0; fi < 4; ++fi)
#pragma unroll
    for (int fj = 0; fj < 4; ++fj) {
      int col = c0 + wc * 64 + fj * 16 + (lane & 15);
      int rowb = r0 + wr * 64 + fi * 16 + (lane >> 4) * 4;
#pragma unroll
      for (int r = 0; r < 4; ++r) {
        size_t idx = (size_t)(rowb + r) * N + col;
        float x = acc[fi][fj][r];
        if constexpr (ACC) x += C[idx];
        if constexpr (EPI) x = gelu_f(x + bias[col]);
        C[idx] = x;
      }
    }
}

// ---------- fused S = Gh@Xh^T; candidates ranked by f32 blend sa*Ae + sb*relu(S) ----------
// grid (64 row-blocks, 8 col-chunks of 1024); 256 thr = 4 waves (2x2)
__global__ __launch_bounds__(256) void s_topk(const unsigned short* __restrict__ Gh,
                                              const unsigned short* __restrict__ Xh,
                                              const float* __restrict__ Ae,
                                              const float* __restrict__ ralpha,
                                              float* __restrict__ pv, int* __restrict__ pix) {
  __shared__ __align__(16) unsigned short As[128 * 64];
  __shared__ __align__(16) unsigned short Bs[128 * 64];
  __shared__ __align__(16) unsigned short St[128 * 136];
  const int r0 = blockIdx.x * 128;
  const int chunk = blockIdx.y;
  const int tid = threadIdx.x, lane = tid & 63, w = tid >> 6;
  const int wr = w >> 1, wc = w & 1;
  const float sa = 1.f / (1.f + expf(-ralpha[0]));
  const float sb = 1.f - sa;
  float lv[16]; int li[16];
#pragma unroll
  for (int q = 0; q < 16; ++q) { lv[q] = -1e30f; li[q] = 0; }

  const int stgrow = w * 32 + (lane >> 3);
  const unsigned short* aSrc = Gh + (size_t)(r0 + stgrow) * 768 + (lane & 7) * 8;
  const int srow = tid & 127, sg = tid >> 7;

  for (int jt = 0; jt < 8; ++jt) {
    const int j0 = chunk * 1024 + jt * 128;
    const unsigned short* bSrc = Xh + (size_t)(j0 + stgrow) * 768 + (lane & 7) * 8;
    f32x4 acc[4][4];
    const f32x4 z4 = {0.f, 0.f, 0.f, 0.f};
#pragma unroll
    for (int i = 0; i < 4; ++i)
#pragma unroll
      for (int j = 0; j < 4; ++j) acc[i][j] = z4;

    for (int k0 = 0; k0 < 768; k0 += 64) {
#pragma unroll
      for (int t = 0; t < 4; ++t) {
        gload16(aSrc + k0 + (size_t)t * 8 * 768, (char*)As + (w * 32 + t * 8) * 128);
        gload16(bSrc + k0 + (size_t)t * 8 * 768, (char*)Bs + (w * 32 + t * 8) * 128);
      }
      __syncthreads();
#pragma unroll
      for (int ks = 0; ks < 2; ++ks) {
        short8v af[4], bf[4];
#pragma unroll
        for (int f = 0; f < 4; ++f) {
          af[f] = *(const short8v*)((const char*)As +
                   (wr * 64 + f * 16 + (lane & 15)) * 128 + ks * 64 + (lane >> 4) * 16);
          bf[f] = *(const short8v*)((const char*)Bs +
                   (wc * 64 + f * 16 + (lane & 15)) * 128 + ks * 64 + (lane >> 4) * 16);
        }
#pragma unroll
        for (int fi = 0; fi < 4; ++fi)
#pragma unroll
          for (int fj = 0; fj < 4; ++fj)
            acc[fi][fj] = __builtin_amdgcn_mfma_f32_16x16x32_bf16(af[fi], bf[fj], acc[fi][fj], 0, 0, 0);
      }
      __syncthreads();
    }
    // store raw S tile to LDS as bf16 (ranking-precision only)
#pragma unroll
    for (int fi = 0; fi < 4; ++fi)
#pragma unroll
      for (int fj = 0; fj < 4; ++fj) {
        int row = wr * 64 + fi * 16 + (lane >> 4) * 4;
        int col = wc * 64 + fj * 16 + (lane & 15);
#pragma unroll
        for (int r = 0; r < 4; ++r)
          St[(row + r) * 136 + col] = f2bf(acc[fi][fj][r]);
      }
    __syncthreads();
    // scan: thread owns (row srow, 64-col half sg); blend Ae (f32 from global) + relu(S)
    const char* base = (const char*)St + srow * 272 + sg * 128;
    const float4* aer = (const float4*)(Ae + (size_t)(r0 + srow) * 8192 + j0 + sg * 64);
#pragma unroll
    for (int cb = 0; cb < 8; ++cb) {
      short8v v8 = *(const short8v*)(base + cb * 16);
      float ea[8];
      *(float4*)&ea[0] = aer[cb * 2];
      *(float4*)&ea[4] = aer[cb * 2 + 1];
#pragma unroll
      for (int e = 0; e < 8; ++e) {
        float s = bf2f((unsigned short)v8[e]);
        float v = sa * ea[e] + sb * fmaxf(s, 0.f);
        if (v > lv[15]) ins16(v, j0 + sg * 64 + cb * 8 + e, lv, li);
      }
    }
    // no barrier needed: next St write is separated by the next K-loop's barriers
  }
  __syncthreads();
  float* StF = (float*)St;
  if (sg == 1) {
#pragma unroll
    for (int q = 0; q < 16; ++q) {
      StF[srow * 32 + q] = lv[q];
      StF[srow * 32 + 16 + q] = __int_as_float(li[q]);
    }
  }
  __syncthreads();
  if (sg == 0) {
#pragma unroll
    for (int q = 0; q < 16; ++q) {
      float v = StF[srow * 32 + q];
      int j = __float_as_int(StF[srow * 32 + 16 + q]);
      if (v > lv[15]) ins16(v, j, lv, li);
    }
    size_t basep = ((size_t)(r0 + srow) * 8 + chunk) * 16;
#pragma unroll
    for (int q = 0; q < 16; ++q) { pv[basep + q] = lv[q]; pix[basep + q] = li[q]; }
  }
}

__global__ __launch_bounds__(256) void merge16(const float* __restrict__ pv,
                                               const int* __restrict__ pix,
                                               int* __restrict__ gidx) {
  int row = blockIdx.x * 256 + threadIdx.x;
  float lv[16]; int li[16];
#pragma unroll
  for (int q = 0; q < 16; ++q) { lv[q] = -1e30f; li[q] = 0; }
  for (int ch = 0; ch < 8; ++ch) {
    size_t base = ((size_t)row * 8 + ch) * 16;
#pragma unroll
    for (int q = 0; q < 16; ++q) {
      float v = pv[base + q];
      if (v > lv[15]) ins16(v, pix[base + q], lv, li);
    }
  }
#pragma unroll
  for (int q = 0; q < 16; ++q) gidx[row * 16 + q] = li[q];
}

// exact f32 re-evaluation of 16 candidates (incl. Ae blend), exact top-5 (ties -> lower index)
__global__ __launch_bounds__(256) void refine5(const float* __restrict__ G,
                                               const float* __restrict__ X,
                                               const float* __restrict__ Ae,
                                               const int* __restrict__ gidx,
                                               const float* __restrict__ ralpha,
                                               int* __restrict__ t5i, float* __restrict__ t5v) {
  int i = blockIdx.x * 4 + (threadIdx.x >> 6);
  int lane = threadIdx.x & 63;
  int c = lane >> 2, s = lane & 3;
  float sa = 1.f / (1.f + expf(-ralpha[0]));
  int j = gidx[i * 16 + c];
  const float* g = G + (size_t)i * 768;
  const float* x = X + (size_t)j * 768;
  float a = 0.f;
#pragma unroll 8
  for (int t = 0; t < 192; ++t) a = fmaf(g[s + 4 * t], x[s + 4 * t], a);
  a += __shfl_xor(a, 1);
  a += __shfl_xor(a, 2);
  float v = sa * Ae[(size_t)i * 8192 + j] + (1.f - sa) * fmaxf(a, 0.f);
  float vs[16]; int js[16];
#pragma unroll
  for (int q = 0; q < 16; ++q) { vs[q] = __shfl(v, q * 4); js[q] = __shfl(j, q * 4); }
  if (lane == 0) {
    unsigned used = 0;
#pragma unroll
    for (int t = 0; t < 5; ++t) {
      float bv = -1e30f; int bj = 0; int bq = 0; bool any = false;
#pragma unroll
      for (int q = 0; q < 16; ++q) {
        bool ok = ((used >> q) & 1u) == 0u;
        bool better = ok && (!any || vs[q] > bv || (vs[q] == bv && js[q] < bj));
        bv = better ? vs[q] : bv; bj = better ? js[q] : bj; bq = better ? q : bq;
        any = any || better;
      }
      used |= (1u << bq);
      t5v[(size_t)i * 5 + t] = bv;
      t5i[(size_t)i * 5 + t] = bj;
    }
  }
}

// -------- symmetrized sparse-A construction (canonical-pair dedup) --------
__global__ void edge_deg(const int* __restrict__ t5i, int* __restrict__ deg) {
  int e = blockIdx.x * 256 + threadIdx.x;
  if (e >= 40960) return;
  int i = e / 5, t = e - i * 5;
  int j = t5i[i * 5 + t];
  if (j == i) return;
  bool rev = false;
#pragma unroll
  for (int u = 0; u < 5; ++u) rev = rev || (t5i[j * 5 + u] == i);
  if (!rev || i < j) { atomicAdd(&deg[i], 1); atomicAdd(&deg[j], 1); }
}

__global__ void scan8k(const int* __restrict__ deg, int* __restrict__ off) {
  __shared__ int sums[256];
  int tid = threadIdx.x;
  int base = tid * 32;
  int s = 0;
  for (int u = 0; u < 32; ++u) s += deg[base + u];
  sums[tid] = s;
  __syncthreads();
  for (int d = 1; d < 256; d <<= 1) {
    int v = (tid >= d) ? sums[tid - d] : 0;
    __syncthreads();
    sums[tid] += v;
    __syncthreads();
  }
  int run = tid ? sums[tid - 1] : 0;
  for (int u = 0; u < 32; ++u) { off[base + u] = run; run += deg[base + u]; }
  if (tid == 255) off[8192] = run;
}

__global__ __launch_bounds__(256) void edge_fill(const int* __restrict__ t5i,
                                                 const float* __restrict__ t5v,
                                                 const float* __restrict__ G,
                                                 const float* __restrict__ X,
                                                 const float* __restrict__ Ae,
                                                 const float* __restrict__ ralpha,
                                                 const int* __restrict__ off,
                                                 int* __restrict__ cursor,
                                                 int* __restrict__ ccol, float* __restrict__ cval) {
  int e = blockIdx.x * 4 + (threadIdx.x >> 6);
  if (e >= 40960) return;
  int lane = threadIdx.x & 63;
  int i = e / 5, t = e - i * 5;
  int j = t5i[i * 5 + t];
  if (j == i) return;
  int rev = -1;
#pragma unroll
  for (int u = 0; u < 5; ++u)
    if (t5i[j * 5 + u] == i) rev = u;
  if (!(rev < 0 || i < j)) return;
  float vji;
  if (rev >= 0) {
    vji = t5v[j * 5 + rev];
  } else {
    const float* g = G + (size_t)j * 768;
    const float* x = X + (size_t)i * 768;
    float a = 0.f;
#pragma unroll
    for (int u = 0; u < 12; ++u) a = fmaf(g[lane + 64 * u], x[lane + 64 * u], a);
#pragma unroll
    for (int d = 32; d; d >>= 1) a += __shfl_xor(a, d);
    float sa = 1.f / (1.f + expf(-ralpha[0]));
    vji = sa * Ae[(size_t)j * 8192 + i] + (1.f - sa) * fmaxf(a, 0.f);
  }
  if (lane == 0) {
    float vij = t5v[i * 5 + t];
    int p0 = off[i] + atomicAdd(&cursor[i], 1);
    ccol[p0] = j; cval[p0] = vij;
    int p1 = off[j] + atomicAdd(&cursor[j], 1);
    ccol[p1] = i; cval[p1] = vji;
  }
}

// M = D^-1 * (X[i] + sum val * X[j]) ; one block per row
__global__ __launch_bounds__(256) void gather_gcn(const float* __restrict__ X,
                                                  const int* __restrict__ off,
                                                  const int* __restrict__ ccol,
                                                  const float* __restrict__ cval,
                                                  float* __restrict__ M) {
  __shared__ float red[256];
  __shared__ float sdinv;
  int i = blockIdx.x, tid = threadIdx.x;
  int s0 = off[i], cnt = off[i + 1] - s0;
  float s = 0.f;
  for (int e = tid; e < cnt; e += 256) s += cval[s0 + e];
  red[tid] = s;
  __syncthreads();
  for (int d = 128; d; d >>= 1) {
    if (tid < d) red[tid] += red[tid + d];
    __syncthreads();
  }
  if (tid == 0) sdinv = 1.f / fmaxf(1.f + red[0], 1e-8f);
  __syncthreads();
  float dinv = sdinv;
  const float* xi = X + (size_t)i * 768;
  float a0 = xi[tid], a1 = xi[tid + 256], a2 = xi[tid + 512];
  for (int e = 0; e < cnt; ++e) {
    float v = cval[s0 + e];
    const float* xr = X + (size_t)ccol[s0 + e] * 768;
    a0 = fmaf(v, xr[tid], a0);
    a1 = fmaf(v, xr[tid + 256], a1);
    a2 = fmaf(v, xr[tid + 512], a2);
  }
  float* mi = M + (size_t)i * 768;
  mi[tid] = a0 * dinv; mi[tid + 256] = a1 * dinv; mi[tid + 512] = a2 * dinv;
}

__global__ __launch_bounds__(256) void final_head(const float* __restrict__ h2,
                                                  const float* __restrict__ W3,
                                                  const float* __restrict__ b3,
                                                  float* __restrict__ out) {
  int i = blockIdx.x * 4 + (threadIdx.x >> 6);
  int lane = threadIdx.x & 63;
  const float* r = h2 + (size_t)i * 256;
  float s = r[lane] * W3[lane] + r[lane + 64] * W3[lane + 64] +
            r[lane + 128] * W3[lane + 128] + r[lane + 192] * W3[lane + 192];
#pragma unroll
  for (int d = 32; d; d >>= 1) s += __shfl_xor(s, d);
  if (lane == 0) out[i] = s + b3[0];
}

extern "C" void kernel_launch(void* const* d_in, const int* in_sizes, int n_in,
                              void* d_out, int out_size, void* d_ws, size_t ws_size,
                              hipStream_t stream) {
  const float* X   = (const float*)d_in[0];
  const float* Ae  = (const float*)d_in[1];
  const float* Wg  = (const float*)d_in[2];
  const float* ra  = (const float*)d_in[3];
  const float* Wgc = (const float*)d_in[4];
  const float* bgc = (const float*)d_in[5];
  const float* W1  = (const float*)d_in[6];
  const float* b1  = (const float*)d_in[7];
  const float* W2  = (const float*)d_in[8];
  const float* b2  = (const float*)d_in[9];
  const float* W3  = (const float*)d_in[10];
  const float* b3  = (const float*)d_in[11];
  float* out = (float*)d_out;

  char* w = (char*)d_ws;
  size_t off_ = 0;
  auto take = [&](size_t n) -> void* {
    void* p = w + off_;
    off_ += (n + 255) & ~(size_t)255;
    return p;
  };
  float* G            = (float*)take((size_t)8192 * 768 * 4);     // 25.17 MB
  unsigned short* Xh  = (unsigned short*)take((size_t)8192 * 768 * 2);  // 12.58
  unsigned short* Gh  = (unsigned short*)take((size_t)8192 * 768 * 2);  // 12.58
  float* pv           = (float*)take((size_t)8192 * 128 * 4);     // 4.19
  int* pix            = (int*)take((size_t)8192 * 128 * 4);       // 4.19
  int* gidx           = (int*)take((size_t)8192 * 16 * 4);
  int* t5i            = (int*)take((size_t)8192 * 5 * 4);
  float* t5v          = (float*)take((size_t)8192 * 5 * 4);
  int* deg            = (int*)take((size_t)8192 * 4);
  int* offr           = (int*)take((size_t)8193 * 4);
  int* cur            = (int*)take((size_t)8192 * 4);
  int* ccol           = (int*)take((size_t)81920 * 4);
  float* cval         = (float*)take((size_t)81920 * 4);
  unsigned short* WcH = (unsigned short*)take((size_t)768 * 768 * 2);
  unsigned short* WcL = (unsigned short*)take((size_t)768 * 768 * 2);
  unsigned short* W1H = (unsigned short*)take((size_t)512 * 768 * 2);
  unsigned short* W1L = (unsigned short*)take((size_t)512 * 768 * 2);
  unsigned short* W2H = (unsigned short*)take((size_t)256 * 512 * 2);
  unsigned short* W2L = (unsigned short*)take((size_t)256 * 512 * 2);
  // total ~65 MB (< R1's proven 85.5 MB)

  // region reuse (all uses strictly ordered by stream):
  // Xh+Gh (25.17 MB, dead after s_topk) hosts: Mf -> Hf -> h1f
  float* Mf  = (float*)Xh;
  float* Hf  = (float*)Xh;
  float* h1f = (float*)Xh;
  // G (25.17 MB, dead after edge_fill) hosts the activation hi/lo planes
  unsigned short* aH = (unsigned short*)G;
  unsigned short* aL = (unsigned short*)((char*)G + (size_t)12582912);
  // pv+pix (8.39 MB, dead after merge16) hosts h2
  float* h2f = (float*)pv;

  // 1. G = X @ Wg — R1-verbatim fp32 kernel (selection depends on this bitwise)
  sgemm_f32<0><<<dim3(64, 6), 256, 0, stream>>>(X, Wg, nullptr, G, 768, 768);
  // 2. bf16 copies for candidate pass
  cvt_bf16<<<6144, 256, 0, stream>>>(X, Xh, 1572864);
  cvt_bf16<<<6144, 256, 0, stream>>>(G, Gh, 1572864);
  // 3. weight planes (needed later; launched early to overlap nothing in particular)
  split_wt<<<dim3(24, 24), 256, 0, stream>>>(Wgc, WcH, WcL, 768, 768);
  split_wt<<<dim3(24, 16), 256, 0, stream>>>(W1, W1H, W1L, 768, 512);
  split_wt<<<dim3(16, 8), 256, 0, stream>>>(W2, W2H, W2L, 512, 256);

  // 4. fused S + per-row top-16 candidates ranked by f32 blend (R1 semantics)
  s_topk<<<dim3(64, 8), 256, 0, stream>>>(Gh, Xh, Ae, ra, pv, pix);
  merge16<<<32, 256, 0, stream>>>(pv, pix, gidx);
  refine5<<<2048, 256, 0, stream>>>(G, X, Ae, gidx, ra, t5i, t5v);

  // 5. sparse symmetric A as CSR
  hipMemsetAsync(deg, 0, 8192 * 4, stream);
  hipMemsetAsync(cur, 0, 8192 * 4, stream);
  edge_deg<<<160, 256, 0, stream>>>(t5i, deg);
  scan8k<<<1, 256, 0, stream>>>(deg, offr);
  edge_fill<<<10240, 256, 0, stream>>>(t5i, t5v, G, X, Ae, ra, offr, cur, ccol, cval);

  // 6. M = A_norm @ X   (writes over Xh+Gh)
  gather_gcn<<<8192, 256, 0, stream>>>(X, offr, ccol, cval, Mf);

  // 7. H = gelu(M @ Wgcn + bgc)  — split-bf16, planes over G (dead now)
  split_act<<<6144, 256, 0, stream>>>(Mf, aH, aL, 1572864);
  gemm_bt<0, 0><<<dim3(64, 6), 256, 0, stream>>>(aH, WcH, nullptr, Hf, 768, 768);
  gemm_bt<1, 0><<<dim3(64, 6), 256, 0, stream>>>(aH, WcL, nullptr, Hf, 768, 768);
  gemm_bt<1, 1><<<dim3(64, 6), 256, 0, stream>>>(aL, WcH, bgc, Hf, 768, 768);

  // 8. h1 = gelu(H @ W1 + b1)
  split_act<<<6144, 256, 0, stream>>>(Hf, aH, aL, 1572864);
  gemm_bt<0, 0><<<dim3(64, 4), 256, 0, stream>>>(aH, W1H, nullptr, h1f, 512, 768);
  gemm_bt<1, 0><<<dim3(64, 4), 256, 0, stream>>>(aH, W1L, nullptr, h1f, 512, 768);
  gemm_bt<1, 1><<<dim3(64, 4), 256, 0, stream>>>(aL, W1H, b1, h1f, 512, 768);

  // 9. h2 = gelu(h1 @ W2 + b2)
  split_act<<<4096, 256, 0, stream>>>(h1f, aH, aL, 1048576);
  gemm_bt<0, 0><<<dim3(64, 2), 256, 0, stream>>>(aH, W2H, nullptr, h2f, 256, 512);
  gemm_bt<1, 0><<<dim3(64, 2), 256, 0, stream>>>(aH, W2L, nullptr, h2f, 256, 512);
  gemm_bt<1, 1><<<dim3(64, 2), 256, 0, stream>>>(aL, W2H, b2, h2f, 256, 512);

  // 10. out = h2 @ W3 + b3
  final_head<<<2048, 256, 0, stream>>>(h2f, W3, b3, out);

  (void)in_sizes; (void)n_in; (void)out_size; (void)ws_size;
}